// Round 2
// baseline (2151.098 us; speedup 1.0000x reference)
//
#include <hip/hip_runtime.h>

#define E_TOT 1600000
#define N_AT  50000

typedef unsigned short u16;
typedef __attribute__((ext_vector_type(8))) __bf16 bf16x8;
typedef __attribute__((ext_vector_type(4))) __bf16 bf16x4;
typedef __attribute__((ext_vector_type(4))) float f32x4;

// Workspace layout (byte offsets), all 16B-aligned:
//   [0,       1024)   sums1 (256 f32)  -- zeroed by k_setup
//   [1024,    1536)   sums2 (128 f32)  -- zeroed by k_setup
//   [2048,   43008)   wf    (20480 bf16, B-fragment order) -- written by k_setup
//   [43008, +12.8M)   ns    (N*64 f32) -- zeroed by k_setup
//   [+,      +6.4M)   ab    (N*64 bf16) -- written by k_setup
//   [+,    +102.4M)   nbrb  (E*32 bf16) -- written by k1
#define SUM1_OFF 0
#define SUM2_OFF 1024
#define WF_OFF   2048
#define NS_OFF   43008
#define AB_OFF   12843008
#define NBRB_OFF 19243008

__device__ __forceinline__ u16 f2bf(float f) {
    unsigned int u = __float_as_uint(f);
    return (u16)((u + 0x7FFFu + ((u >> 16) & 1u)) >> 16);
}
__device__ __forceinline__ float softplus_f(float x) {
    return fmaxf(x, 0.0f) + __logf(1.0f + __expf(-fabsf(x)));
}
__device__ __forceinline__ bf16x8 cvt8v(f32x4 a, f32x4 b) {
    bf16x8 r;
    r[0] = (__bf16)a[0]; r[1] = (__bf16)a[1]; r[2] = (__bf16)a[2]; r[3] = (__bf16)a[3];
    r[4] = (__bf16)b[0]; r[5] = (__bf16)b[1]; r[6] = (__bf16)b[2]; r[7] = (__bf16)b[3];
    return r;
}

// ---------------------------------------------------------------------------
// k_setup: zero sums1/sums2/ns + cvt atom->ab + swizzle W->wf
// ---------------------------------------------------------------------------
__global__ __launch_bounds__(256) void k_setup(const float* __restrict__ atom,
                                               const float* __restrict__ W,
                                               char* __restrict__ ws) {
    u16* wf   = (u16*)(ws + WF_OFF);
    float* ns = (float*)(ws + NS_OFF);
    u16* ab   = (u16*)(ws + AB_OFF);
    const int tid = blockIdx.x * 256 + threadIdx.x;
    const int gsz = gridDim.x * 256;

    for (int i = tid; i < 512; i += gsz) ((float*)ws)[i] = 0.0f;  // sums1+sums2

    f32x4 z = {0.f, 0.f, 0.f, 0.f};
    for (int i = tid; i < N_AT * 64 / 4; i += gsz) ((f32x4*)ns)[i] = z;

    for (int i = tid; i < N_AT * 64 / 4; i += gsz) {
        f32x4 v = ((const f32x4*)atom)[i];
        bf16x4 h;
        h[0] = (__bf16)v[0]; h[1] = (__bf16)v[1];
        h[2] = (__bf16)v[2]; h[3] = (__bf16)v[3];
        *(bf16x4*)(ab + i * 4) = h;
    }

    for (int t = tid; t < 20480; t += gsz) {
        int j = t & 7, l2 = (t >> 3) & 63, ct = (t >> 9) & 7, kt = t >> 12;
        int k = kt * 32 + (l2 >> 4) * 8 + j;
        int c = ct * 16 + (l2 & 15);
        wf[t] = f2bf(W[k * 128 + c]);
    }
}

// ---------------------------------------------------------------------------
// k1: GEMM pass 1 (stats) + nbr->bf16 cvt. 512 thr = 8 waves, 32 rows/wave.
// R1: W is NOT staged in LDS -- wf (40KB) is L2-resident and read identically
// by every wave, so B fragments come straight from global (coalesced 1KB/instr,
// ~100% L2 hit). LDS -> 1KB, VGPR=64 -> 8 waves/SIMD = 32 waves/CU (was 16).
// No barrier before the GEMM: waves run fully decoupled for latency hiding.
// ---------------------------------------------------------------------------
__global__ __launch_bounds__(512, 8) void k1_stats(const u16* __restrict__ ab,
                                                   const float* __restrict__ nbr,
                                                   u16* __restrict__ nbrb,
                                                   const int* __restrict__ sidx,
                                                   const int* __restrict__ nidx,
                                                   const u16* __restrict__ wf,
                                                   float* __restrict__ sums1) {
    __shared__ float bs[256];
    const int tx = threadIdx.x, lane = tx & 63, w = tx >> 6;
    const int mrow = lane & 15, quad = lane >> 4;

    if (tx < 256) bs[tx] = 0.0f;

    const int rb = blockIdx.x * 256 + w * 32;
    const int r0 = rb + mrow, r1 = r0 + 16;
    const int s0 = sidx[r0], s1 = sidx[r1];
    const int n0 = nidx[r0], n1 = nidx[r1];
    const u16* pa0 = ab + (size_t)s0 * 64 + quad * 8;
    const u16* pa1 = ab + (size_t)s1 * 64 + quad * 8;
    const u16* pb0 = ab + (size_t)n0 * 64 + quad * 8;
    const u16* pb1 = ab + (size_t)n1 * 64 + quad * 8;

    // Issue the long-latency loads (random nidx gather + nbr f32) first.
    bf16x8 pf_b00 = *(const bf16x8*)(pb0);
    bf16x8 pf_b01 = *(const bf16x8*)(pb0 + 32);
    bf16x8 pf_b10 = *(const bf16x8*)(pb1);
    bf16x8 pf_b11 = *(const bf16x8*)(pb1 + 32);
    const float* p0 = nbr + (size_t)r0 * 32 + quad * 8;
    const float* p1 = nbr + (size_t)r1 * 32 + quad * 8;
    f32x4 pf_n00 = *(const f32x4*)p0;
    f32x4 pf_n01 = *(const f32x4*)(p0 + 4);
    f32x4 pf_n10 = *(const f32x4*)p1;
    f32x4 pf_n11 = *(const f32x4*)(p1 + 4);

    f32x4 acc[2][8];
#pragma unroll
    for (int rf = 0; rf < 2; rf++)
#pragma unroll
        for (int ct = 0; ct < 8; ct++) { f32x4 z = {0.f, 0.f, 0.f, 0.f}; acc[rf][ct] = z; }

#pragma unroll
    for (int kt = 0; kt < 5; kt++) {
        bf16x8 a0, a1;
        if (kt < 2) {
            a0 = *(const bf16x8*)(pa0 + kt * 32);   // sorted sidx: L2-hot
            a1 = *(const bf16x8*)(pa1 + kt * 32);
        } else if (kt == 2) {
            a0 = pf_b00; a1 = pf_b10;
        } else if (kt == 3) {
            a0 = pf_b01; a1 = pf_b11;
        } else {
            a0 = cvt8v(pf_n00, pf_n01);
            a1 = cvt8v(pf_n10, pf_n11);
            *(bf16x8*)(nbrb + (size_t)r0 * 32 + quad * 8) = a0;
            *(bf16x8*)(nbrb + (size_t)r1 * 32 + quad * 8) = a1;
        }
#pragma unroll
        for (int ct = 0; ct < 8; ct++) {
            bf16x8 b = *(const bf16x8*)&wf[((kt * 8 + ct) * 64 + lane) * 8];
            acc[0][ct] = __builtin_amdgcn_mfma_f32_16x16x32_bf16(a0, b, acc[0][ct], 0, 0, 0);
            acc[1][ct] = __builtin_amdgcn_mfma_f32_16x16x32_bf16(a1, b, acc[1][ct], 0, 0, 0);
        }
    }

    __syncthreads();   // bs zero visible before block-level accumulation

    // Stats: C/D col = ct*16+mrow; reduce rows over quads via shfl
#pragma unroll
    for (int ct = 0; ct < 8; ct++) {
        float s = 0.f, q = 0.f;
#pragma unroll
        for (int rf = 0; rf < 2; rf++)
#pragma unroll
            for (int rg = 0; rg < 4; rg++) {
                float v = acc[rf][ct][rg];
                s += v; q += v * v;
            }
        s += __shfl_xor(s, 16, 64); s += __shfl_xor(s, 32, 64);
        q += __shfl_xor(q, 16, 64); q += __shfl_xor(q, 32, 64);
        if (quad == 0) {
            atomicAdd(&bs[ct * 16 + mrow], s);
            atomicAdd(&bs[128 + ct * 16 + mrow], q);
        }
    }
    __syncthreads();
    if (tx < 256) atomicAdd(&sums1[tx], bs[tx]);
}

// ---------------------------------------------------------------------------
// k3: GEMM pass 2 + BN1 + sigmoid*softplus + segment-sum. 512 thr = 8 waves.
// R1: no LDS W (read wf from L2), no barriers at all (msgb is per-wave).
// LDS = 33.8KB msg -> 4 blocks/CU, VGPR=64 -> 32 waves/CU (100%).
// ---------------------------------------------------------------------------
__global__ __launch_bounds__(512, 8) void k3_msg(const u16* __restrict__ ab,
                                                 const u16* __restrict__ nbrb,
                                                 const int* __restrict__ sidx,
                                                 const int* __restrict__ nidx,
                                                 const u16* __restrict__ wf,
                                                 const float* __restrict__ sums1,
                                                 const float* __restrict__ g1,
                                                 const float* __restrict__ b1,
                                                 float* __restrict__ ns) {
    __shared__ float msgb[8][16 * 66];  // 33.8 KB, per-wave region
    const int tx = threadIdx.x, lane = tx & 63, w = tx >> 6;
    const int mrow = lane & 15, quad = lane >> 4;

    const int rb = blockIdx.x * 256 + w * 32;
    const int r0 = rb + mrow, r1 = r0 + 16;
    const int s0 = sidx[r0], s1 = sidx[r1];
    const int n0 = nidx[r0], n1 = nidx[r1];
    const u16* pa0 = ab + (size_t)s0 * 64 + quad * 8;
    const u16* pa1 = ab + (size_t)s1 * 64 + quad * 8;
    const u16* pb0 = ab + (size_t)n0 * 64 + quad * 8;
    const u16* pb1 = ab + (size_t)n1 * 64 + quad * 8;

    bf16x8 pf_b00 = *(const bf16x8*)(pb0);
    bf16x8 pf_b01 = *(const bf16x8*)(pb0 + 32);
    bf16x8 pf_b10 = *(const bf16x8*)(pb1);
    bf16x8 pf_b11 = *(const bf16x8*)(pb1 + 32);
    bf16x8 pf_nb0 = *(const bf16x8*)(nbrb + (size_t)r0 * 32 + quad * 8);
    bf16x8 pf_nb1 = *(const bf16x8*)(nbrb + (size_t)r1 * 32 + quad * 8);

    f32x4 acc[2][8];
#pragma unroll
    for (int rf = 0; rf < 2; rf++)
#pragma unroll
        for (int ct = 0; ct < 8; ct++) { f32x4 z = {0.f, 0.f, 0.f, 0.f}; acc[rf][ct] = z; }

#pragma unroll
    for (int kt = 0; kt < 5; kt++) {
        bf16x8 a0, a1;
        if (kt < 2) {
            a0 = *(const bf16x8*)(pa0 + kt * 32);
            a1 = *(const bf16x8*)(pa1 + kt * 32);
        } else if (kt == 2) {
            a0 = pf_b00; a1 = pf_b10;
        } else if (kt == 3) {
            a0 = pf_b01; a1 = pf_b11;
        } else {
            a0 = pf_nb0; a1 = pf_nb1;
        }
#pragma unroll
        for (int ct = 0; ct < 8; ct++) {
            bf16x8 b = *(const bf16x8*)&wf[((kt * 8 + ct) * 64 + lane) * 8];
            acc[0][ct] = __builtin_amdgcn_mfma_f32_16x16x32_bf16(a0, b, acc[0][ct], 0, 0, 0);
            acc[1][ct] = __builtin_amdgcn_mfma_f32_16x16x32_bf16(a1, b, acc[1][ct], 0, 0, 0);
        }
    }

    // BN1 affine constants (fc bias b cancels exactly under training-mode BN)
    const float invE = 1.0f / (float)E_TOT;
    float af[4], kf[4], ac[4], kc[4];
#pragma unroll
    for (int ct = 0; ct < 4; ct++) {
        int cf = ct * 16 + mrow, cc = cf + 64;
        float mf = sums1[cf] * invE;
        float vf = sums1[128 + cf] * invE - mf * mf;
        af[ct] = g1[cf] * rsqrtf(vf + 1e-5f);
        kf[ct] = b1[cf] - af[ct] * mf;
        float mc = sums1[cc] * invE;
        float vc = sums1[128 + cc] * invE - mc * mc;
        ac[ct] = g1[cc] * rsqrtf(vc + 1e-5f);
        kc[ct] = b1[cc] - ac[ct] * mc;
    }

    // Epilogue per 16-row half-tile: gate -> same-wave LDS transpose -> scan
    float* mw = msgb[w];
#pragma unroll
    for (int rf = 0; rf < 2; rf++) {
#pragma unroll
        for (int ct = 0; ct < 4; ct++) {
#pragma unroll
            for (int rg = 0; rg < 4; rg++) {
                // C/D layout: row = quad*4+rg (+16*rf), col = mrow (+16*ct)
                float xf = af[ct] * acc[rf][ct][rg] + kf[ct];
                float xc = ac[ct] * acc[rf][ct + 4][rg] + kc[ct];
                float sg = 1.0f / (1.0f + __expf(-xf));
                mw[(quad * 4 + rg) * 66 + ct * 16 + mrow] = sg * softplus_f(xc);
            }
        }
        const int ebase = rb + rf * 16;
        float mv[16];
#pragma unroll
        for (int i = 0; i < 16; i++) mv[i] = mw[i * 66 + lane];
        float accum = 0.f;
        int cur = sidx[ebase];
#pragma unroll
        for (int i = 0; i < 16; i++) {
            int idx = sidx[ebase + i];   // wave-uniform -> scalar loads
            if (idx != cur) {
                atomicAdd(&ns[(size_t)cur * 64 + lane], accum);
                accum = 0.f;
                cur = idx;
            }
            accum += mv[i];
        }
        atomicAdd(&ns[(size_t)cur * 64 + lane], accum);
    }
}

// ---------------------------------------------------------------------------
// k4: BN2 stats over nbr_sumed (N x 64 f32) -> sums2[128]
// ---------------------------------------------------------------------------
__global__ __launch_bounds__(256) void k4_bn2stats(const float* __restrict__ ns,
                                                   float* __restrict__ sums2) {
    const int tx = threadIdx.x;
    const int col = tx & 63, rg = tx >> 6;
    float s = 0.f, q = 0.f;
    for (int r = blockIdx.x * 4 + rg; r < N_AT; r += 256 * 4) {
        float v = ns[r * 64 + col];
        s += v; q += v * v;
    }
    atomicAdd(&sums2[col], s);
    atomicAdd(&sums2[64 + col], q);
}

// ---------------------------------------------------------------------------
// k5: out = softplus(atom + BN2(nbr_sumed))
// ---------------------------------------------------------------------------
__global__ __launch_bounds__(256) void k5_final(const float* __restrict__ atom,
                                                const float* __restrict__ ns,
                                                const float* __restrict__ sums2,
                                                const float* __restrict__ g2,
                                                const float* __restrict__ b2,
                                                float* __restrict__ out) {
    const int i = blockIdx.x * 256 + threadIdx.x;  // grid covers N*64 exactly
    const int col = i & 63;
    const float invN = 1.0f / (float)N_AT;
    float mean = sums2[col] * invN;
    float var = sums2[64 + col] * invN - mean * mean;
    float a2 = g2[col] * rsqrtf(var + 1e-5f);
    float c2 = b2[col] - a2 * mean;
    out[i] = softplus_f(atom[i] + a2 * ns[i] + c2);
}

extern "C" void kernel_launch(void* const* d_in, const int* in_sizes, int n_in,
                              void* d_out, int out_size, void* d_ws, size_t ws_size,
                              hipStream_t stream) {
    const float* atom = (const float*)d_in[0];
    const float* nbr  = (const float*)d_in[1];
    const int* sidx   = (const int*)d_in[2];
    const int* nidx   = (const int*)d_in[3];
    const float* W    = (const float*)d_in[4];
    // d_in[5] = b : cancels exactly under training-mode BN1 -> unused
    const float* g1   = (const float*)d_in[6];
    const float* b1   = (const float*)d_in[7];
    const float* g2   = (const float*)d_in[8];
    const float* b2   = (const float*)d_in[9];
    float* out = (float*)d_out;

    char* ws = (char*)d_ws;
    float* sums1 = (float*)(ws + SUM1_OFF);
    float* sums2 = (float*)(ws + SUM2_OFF);
    u16*   wf    = (u16*)(ws + WF_OFF);
    float* nsum  = (float*)(ws + NS_OFF);
    u16*   ab    = (u16*)(ws + AB_OFF);
    u16*   nbrb  = (u16*)(ws + NBRB_OFF);

    k_setup<<<1024, 256, 0, stream>>>(atom, W, ws);
    k1_stats<<<E_TOT / 256, 512, 0, stream>>>(ab, nbr, nbrb, sidx, nidx, wf, sums1);
    k3_msg<<<E_TOT / 256, 512, 0, stream>>>(ab, nbrb, sidx, nidx, wf, sums1, g1, b1, nsum);
    k4_bn2stats<<<256, 256, 0, stream>>>(nsum, sums2);
    k5_final<<<(N_AT * 64) / 256, 256, 0, stream>>>(atom, nsum, sums2, g2, b2, out);
}

// Round 3
// 920.777 us; speedup vs baseline: 2.3362x; 2.3362x over previous
//
#include <hip/hip_runtime.h>

#define E_TOT 1600000
#define N_AT  50000

typedef unsigned short u16;
typedef __attribute__((ext_vector_type(8))) __bf16 bf16x8;
typedef __attribute__((ext_vector_type(4))) __bf16 bf16x4;
typedef __attribute__((ext_vector_type(4))) float f32x4;

// Workspace layout (byte offsets), all 16B-aligned:
//   [0,       1024)   sums1 (256 f32)  -- zeroed by k_setup
//   [1024,    1536)   sums2 (128 f32)  -- zeroed by k_setup
//   [2048,   43008)   wf    (20480 bf16, B-fragment order) -- written by k_setup
//   [43008, +12.8M)   ns    (N*64 f32) -- zeroed by k_setup
//   [+,      +6.4M)   ab    (N*64 bf16) -- written by k_setup
//   [+,    +102.4M)   nbrb  (E*32 bf16) -- written by k1
#define SUM1_OFF 0
#define SUM2_OFF 1024
#define WF_OFF   2048
#define NS_OFF   43008
#define AB_OFF   12843008
#define NBRB_OFF 19243008

__device__ __forceinline__ u16 f2bf(float f) {
    unsigned int u = __float_as_uint(f);
    return (u16)((u + 0x7FFFu + ((u >> 16) & 1u)) >> 16);
}
__device__ __forceinline__ float softplus_f(float x) {
    return fmaxf(x, 0.0f) + __logf(1.0f + __expf(-fabsf(x)));
}
__device__ __forceinline__ bf16x8 cvt8v(f32x4 a, f32x4 b) {
    bf16x8 r;
    r[0] = (__bf16)a[0]; r[1] = (__bf16)a[1]; r[2] = (__bf16)a[2]; r[3] = (__bf16)a[3];
    r[4] = (__bf16)b[0]; r[5] = (__bf16)b[1]; r[6] = (__bf16)b[2]; r[7] = (__bf16)b[3];
    return r;
}

// ---------------------------------------------------------------------------
// k_setup: zero sums1/sums2/ns + cvt atom->ab + swizzle W->wf
// ---------------------------------------------------------------------------
__global__ __launch_bounds__(256) void k_setup(const float* __restrict__ atom,
                                               const float* __restrict__ W,
                                               char* __restrict__ ws) {
    u16* wf   = (u16*)(ws + WF_OFF);
    float* ns = (float*)(ws + NS_OFF);
    u16* ab   = (u16*)(ws + AB_OFF);
    const int tid = blockIdx.x * 256 + threadIdx.x;
    const int gsz = gridDim.x * 256;

    for (int i = tid; i < 512; i += gsz) ((float*)ws)[i] = 0.0f;  // sums1+sums2

    f32x4 z = {0.f, 0.f, 0.f, 0.f};
    for (int i = tid; i < N_AT * 64 / 4; i += gsz) ((f32x4*)ns)[i] = z;

    for (int i = tid; i < N_AT * 64 / 4; i += gsz) {
        f32x4 v = ((const f32x4*)atom)[i];
        bf16x4 h;
        h[0] = (__bf16)v[0]; h[1] = (__bf16)v[1];
        h[2] = (__bf16)v[2]; h[3] = (__bf16)v[3];
        *(bf16x4*)(ab + i * 4) = h;
    }

    for (int t = tid; t < 20480; t += gsz) {
        int j = t & 7, l2 = (t >> 3) & 63, ct = (t >> 9) & 7, kt = t >> 12;
        int k = kt * 32 + (l2 >> 4) * 8 + j;
        int c = ct * 16 + (l2 & 15);
        wf[t] = f2bf(W[k * 128 + c]);
    }
}

// ---------------------------------------------------------------------------
// k1: GEMM pass 1 (stats) + nbr->bf16 cvt.
// R2: 16 rows/wave (acc[8] = 32 VGPR, was 64) so __launch_bounds__(512,6)
// fits WITHOUT spilling (R1's (512,8) forced 64-reg cap -> acc spilled to
// scratch -> 3.8GB HBM traffic). 24 waves/CU target. W read straight from
// L2-resident wf (no LDS staging, no pre-GEMM barrier).
// ---------------------------------------------------------------------------
__global__ __launch_bounds__(512, 6) void k1_stats(const u16* __restrict__ ab,
                                                   const float* __restrict__ nbr,
                                                   u16* __restrict__ nbrb,
                                                   const int* __restrict__ sidx,
                                                   const int* __restrict__ nidx,
                                                   const u16* __restrict__ wf,
                                                   float* __restrict__ sums1) {
    __shared__ float bs[256];
    const int tx = threadIdx.x, lane = tx & 63, w = tx >> 6;
    const int mrow = lane & 15, quad = lane >> 4;

    if (tx < 256) bs[tx] = 0.0f;

    const int r0 = blockIdx.x * 128 + w * 16 + mrow;
    const int s0 = sidx[r0];
    const int n0 = nidx[r0];
    const u16* pa0 = ab + (size_t)s0 * 64 + quad * 8;
    const u16* pb0 = ab + (size_t)n0 * 64 + quad * 8;
    const float* p0 = nbr + (size_t)r0 * 32 + quad * 8;

    // All 5 A-fragments issued up front: gathers + nbr fly together (MLP).
    bf16x8 a0 = *(const bf16x8*)(pa0);
    bf16x8 a1 = *(const bf16x8*)(pa0 + 32);
    bf16x8 a2 = *(const bf16x8*)(pb0);
    bf16x8 a3 = *(const bf16x8*)(pb0 + 32);
    bf16x8 a4 = cvt8v(*(const f32x4*)p0, *(const f32x4*)(p0 + 4));
    *(bf16x8*)(nbrb + (size_t)r0 * 32 + quad * 8) = a4;

    f32x4 acc[8];
#pragma unroll
    for (int ct = 0; ct < 8; ct++) { f32x4 z = {0.f, 0.f, 0.f, 0.f}; acc[ct] = z; }

#pragma unroll
    for (int kt = 0; kt < 5; kt++) {
        bf16x8 a = (kt == 0) ? a0 : (kt == 1) ? a1 : (kt == 2) ? a2 : (kt == 3) ? a3 : a4;
#pragma unroll
        for (int ct = 0; ct < 8; ct++) {
            bf16x8 b = *(const bf16x8*)&wf[((kt * 8 + ct) * 64 + lane) * 8];
            acc[ct] = __builtin_amdgcn_mfma_f32_16x16x32_bf16(a, b, acc[ct], 0, 0, 0);
        }
    }

    __syncthreads();   // bs zero visible before block-level accumulation

    // Stats: C/D col = ct*16+mrow, row = quad*4+rg; reduce rows via shfl
#pragma unroll
    for (int ct = 0; ct < 8; ct++) {
        float s = 0.f, q = 0.f;
#pragma unroll
        for (int rg = 0; rg < 4; rg++) {
            float v = acc[ct][rg];
            s += v; q += v * v;
        }
        s += __shfl_xor(s, 16, 64); s += __shfl_xor(s, 32, 64);
        q += __shfl_xor(q, 16, 64); q += __shfl_xor(q, 32, 64);
        if (quad == 0) {
            atomicAdd(&bs[ct * 16 + mrow], s);
            atomicAdd(&bs[128 + ct * 16 + mrow], q);
        }
    }
    __syncthreads();
    if (tx < 256) atomicAdd(&sums1[tx], bs[tx]);
}

// ---------------------------------------------------------------------------
// k3: GEMM pass 2 + BN1 + sigmoid*softplus + segment-sum.
// R2: 16 rows/wave (acc[8]), (512,6), wf from L2, ZERO barriers (msgb is
// per-wave). Scan reads LDS directly (no mv[16] register block).
// LDS = 8 waves x 16x66 f32 = 33.8 KB.
// ---------------------------------------------------------------------------
__global__ __launch_bounds__(512, 6) void k3_msg(const u16* __restrict__ ab,
                                                 const u16* __restrict__ nbrb,
                                                 const int* __restrict__ sidx,
                                                 const int* __restrict__ nidx,
                                                 const u16* __restrict__ wf,
                                                 const float* __restrict__ sums1,
                                                 const float* __restrict__ g1,
                                                 const float* __restrict__ b1,
                                                 float* __restrict__ ns) {
    __shared__ float msgb[8][16 * 66];  // per-wave region
    const int tx = threadIdx.x, lane = tx & 63, w = tx >> 6;
    const int mrow = lane & 15, quad = lane >> 4;

    const int rb = blockIdx.x * 128 + w * 16;
    const int r0 = rb + mrow;
    const int s0 = sidx[r0];
    const int n0 = nidx[r0];
    const u16* pa0 = ab + (size_t)s0 * 64 + quad * 8;
    const u16* pb0 = ab + (size_t)n0 * 64 + quad * 8;

    bf16x8 a0 = *(const bf16x8*)(pa0);
    bf16x8 a1 = *(const bf16x8*)(pa0 + 32);
    bf16x8 a2 = *(const bf16x8*)(pb0);
    bf16x8 a3 = *(const bf16x8*)(pb0 + 32);
    bf16x8 a4 = *(const bf16x8*)(nbrb + (size_t)r0 * 32 + quad * 8);

    f32x4 acc[8];
#pragma unroll
    for (int ct = 0; ct < 8; ct++) { f32x4 z = {0.f, 0.f, 0.f, 0.f}; acc[ct] = z; }

#pragma unroll
    for (int kt = 0; kt < 5; kt++) {
        bf16x8 a = (kt == 0) ? a0 : (kt == 1) ? a1 : (kt == 2) ? a2 : (kt == 3) ? a3 : a4;
#pragma unroll
        for (int ct = 0; ct < 8; ct++) {
            bf16x8 b = *(const bf16x8*)&wf[((kt * 8 + ct) * 64 + lane) * 8];
            acc[ct] = __builtin_amdgcn_mfma_f32_16x16x32_bf16(a, b, acc[ct], 0, 0, 0);
        }
    }

    // BN1 affine constants (fc bias b cancels exactly under training-mode BN)
    const float invE = 1.0f / (float)E_TOT;
    float* mw = msgb[w];
#pragma unroll
    for (int ct = 0; ct < 4; ct++) {
        int cf = ct * 16 + mrow, cc = cf + 64;
        float mf = sums1[cf] * invE;
        float vf = sums1[128 + cf] * invE - mf * mf;
        float af = g1[cf] * rsqrtf(vf + 1e-5f);
        float kf = b1[cf] - af * mf;
        float mc = sums1[cc] * invE;
        float vc = sums1[128 + cc] * invE - mc * mc;
        float ac = g1[cc] * rsqrtf(vc + 1e-5f);
        float kc = b1[cc] - ac * mc;
#pragma unroll
        for (int rg = 0; rg < 4; rg++) {
            // C/D layout: row = quad*4+rg, col = mrow (+16*ct)
            float xf = af * acc[ct][rg] + kf;
            float xc = ac * acc[ct + 4][rg] + kc;
            float sg = 1.0f / (1.0f + __expf(-xf));
            mw[(quad * 4 + rg) * 66 + ct * 16 + mrow] = sg * softplus_f(xc);
        }
    }

    // Segment-sum scan over the wave's 16 rows (LDS transpose read: lane=col)
    float accum = 0.f;
    int cur = sidx[rb];
#pragma unroll
    for (int i = 0; i < 16; i++) {
        int idx = sidx[rb + i];   // wave-uniform -> scalar loads
        if (idx != cur) {
            atomicAdd(&ns[(size_t)cur * 64 + lane], accum);
            accum = 0.f;
            cur = idx;
        }
        accum += mw[i * 66 + lane];
    }
    atomicAdd(&ns[(size_t)cur * 64 + lane], accum);
}

// ---------------------------------------------------------------------------
// k4: BN2 stats over nbr_sumed (N x 64 f32) -> sums2[128]
// ---------------------------------------------------------------------------
__global__ __launch_bounds__(256) void k4_bn2stats(const float* __restrict__ ns,
                                                   float* __restrict__ sums2) {
    const int tx = threadIdx.x;
    const int col = tx & 63, rg = tx >> 6;
    float s = 0.f, q = 0.f;
    for (int r = blockIdx.x * 4 + rg; r < N_AT; r += 256 * 4) {
        float v = ns[r * 64 + col];
        s += v; q += v * v;
    }
    atomicAdd(&sums2[col], s);
    atomicAdd(&sums2[64 + col], q);
}

// ---------------------------------------------------------------------------
// k5: out = softplus(atom + BN2(nbr_sumed))
// ---------------------------------------------------------------------------
__global__ __launch_bounds__(256) void k5_final(const float* __restrict__ atom,
                                                const float* __restrict__ ns,
                                                const float* __restrict__ sums2,
                                                const float* __restrict__ g2,
                                                const float* __restrict__ b2,
                                                float* __restrict__ out) {
    const int i = blockIdx.x * 256 + threadIdx.x;  // grid covers N*64 exactly
    const int col = i & 63;
    const float invN = 1.0f / (float)N_AT;
    float mean = sums2[col] * invN;
    float var = sums2[64 + col] * invN - mean * mean;
    float a2 = g2[col] * rsqrtf(var + 1e-5f);
    float c2 = b2[col] - a2 * mean;
    out[i] = softplus_f(atom[i] + a2 * ns[i] + c2);
}

extern "C" void kernel_launch(void* const* d_in, const int* in_sizes, int n_in,
                              void* d_out, int out_size, void* d_ws, size_t ws_size,
                              hipStream_t stream) {
    const float* atom = (const float*)d_in[0];
    const float* nbr  = (const float*)d_in[1];
    const int* sidx   = (const int*)d_in[2];
    const int* nidx   = (const int*)d_in[3];
    const float* W    = (const float*)d_in[4];
    // d_in[5] = b : cancels exactly under training-mode BN1 -> unused
    const float* g1   = (const float*)d_in[6];
    const float* b1   = (const float*)d_in[7];
    const float* g2   = (const float*)d_in[8];
    const float* b2   = (const float*)d_in[9];
    float* out = (float*)d_out;

    char* ws = (char*)d_ws;
    float* sums1 = (float*)(ws + SUM1_OFF);
    float* sums2 = (float*)(ws + SUM2_OFF);
    u16*   wf    = (u16*)(ws + WF_OFF);
    float* nsum  = (float*)(ws + NS_OFF);
    u16*   ab    = (u16*)(ws + AB_OFF);
    u16*   nbrb  = (u16*)(ws + NBRB_OFF);

    k_setup<<<1024, 256, 0, stream>>>(atom, W, ws);
    k1_stats<<<E_TOT / 128, 512, 0, stream>>>(ab, nbr, nbrb, sidx, nidx, wf, sums1);
    k3_msg<<<E_TOT / 128, 512, 0, stream>>>(ab, nbrb, sidx, nidx, wf, sums1, g1, b1, nsum);
    k4_bn2stats<<<256, 256, 0, stream>>>(nsum, sums2);
    k5_final<<<(N_AT * 64) / 256, 256, 0, stream>>>(atom, nsum, sums2, g2, b2, out);
}

// Round 4
// 832.446 us; speedup vs baseline: 2.5841x; 1.1061x over previous
//
#include <hip/hip_runtime.h>

#define E_TOT 1600000
#define N_AT  50000

typedef unsigned short u16;
typedef __attribute__((ext_vector_type(8))) __bf16 bf16x8;
typedef __attribute__((ext_vector_type(4))) __bf16 bf16x4;
typedef __attribute__((ext_vector_type(4))) float f32x4;

// Workspace layout (byte offsets), all 16B-aligned:
//   [0,       1024)   sums1 (256 f32)  -- zeroed by k_setup
//   [1024,    1536)   sums2 (128 f32)  -- zeroed by k_setup
//   [2048,   43008)   wf    (20480 bf16, B-fragment order) -- written by k_setup
//   [43008, +12.8M)   ns    (N*64 f32) -- zeroed by k_setup
//   [+,      +6.4M)   ab    (N*64 bf16) -- written by k_setup
//   [+,    +102.4M)   nbrb  (E*32 bf16) -- written by k1
#define SUM1_OFF 0
#define SUM2_OFF 1024
#define WF_OFF   2048
#define NS_OFF   43008
#define AB_OFF   12843008
#define NBRB_OFF 19243008

__device__ __forceinline__ u16 f2bf(float f) {
    unsigned int u = __float_as_uint(f);
    return (u16)((u + 0x7FFFu + ((u >> 16) & 1u)) >> 16);
}
__device__ __forceinline__ float softplus_f(float x) {
    return fmaxf(x, 0.0f) + __logf(1.0f + __expf(-fabsf(x)));
}
__device__ __forceinline__ bf16x8 cvt8v(f32x4 a, f32x4 b) {
    bf16x8 r;
    r[0] = (__bf16)a[0]; r[1] = (__bf16)a[1]; r[2] = (__bf16)a[2]; r[3] = (__bf16)a[3];
    r[4] = (__bf16)b[0]; r[5] = (__bf16)b[1]; r[6] = (__bf16)b[2]; r[7] = (__bf16)b[3];
    return r;
}

// ---------------------------------------------------------------------------
// k_setup: zero sums1/sums2/ns + cvt atom->ab + swizzle W->wf
// ---------------------------------------------------------------------------
__global__ __launch_bounds__(256) void k_setup(const float* __restrict__ atom,
                                               const float* __restrict__ W,
                                               char* __restrict__ ws) {
    u16* wf   = (u16*)(ws + WF_OFF);
    float* ns = (float*)(ws + NS_OFF);
    u16* ab   = (u16*)(ws + AB_OFF);
    const int tid = blockIdx.x * 256 + threadIdx.x;
    const int gsz = gridDim.x * 256;

    for (int i = tid; i < 512; i += gsz) ((float*)ws)[i] = 0.0f;  // sums1+sums2

    f32x4 z = {0.f, 0.f, 0.f, 0.f};
    for (int i = tid; i < N_AT * 64 / 4; i += gsz) ((f32x4*)ns)[i] = z;

    for (int i = tid; i < N_AT * 64 / 4; i += gsz) {
        f32x4 v = ((const f32x4*)atom)[i];
        bf16x4 h;
        h[0] = (__bf16)v[0]; h[1] = (__bf16)v[1];
        h[2] = (__bf16)v[2]; h[3] = (__bf16)v[3];
        *(bf16x4*)(ab + i * 4) = h;
    }

    for (int t = tid; t < 20480; t += gsz) {
        int j = t & 7, l2 = (t >> 3) & 63, ct = (t >> 9) & 7, kt = t >> 12;
        int k = kt * 32 + (l2 >> 4) * 8 + j;
        int c = ct * 16 + (l2 & 15);
        wf[t] = f2bf(W[k * 128 + c]);
    }
}

// ---------------------------------------------------------------------------
// k1: GEMM pass 1 (stats) + nbr->bf16 cvt.
// R3: W back in LDS (R2's per-MFMA L2 b-reads were latency-bound: VALU 8%,
// MFMA 6%, k1=403us). 16 rows/wave (acc[8]=32 VGPR) keeps (512,6) spill-free.
// LDS = 40KB W + 1KB bs -> 3 blocks/CU = 24 waves (75%), vs 2 blocks in R0.
// A-gathers issue BEFORE the staging barrier (latency hides under staging).
// ---------------------------------------------------------------------------
__global__ __launch_bounds__(512, 6) void k1_stats(const u16* __restrict__ ab,
                                                   const float* __restrict__ nbr,
                                                   u16* __restrict__ nbrb,
                                                   const int* __restrict__ sidx,
                                                   const int* __restrict__ nidx,
                                                   const u16* __restrict__ wf,
                                                   float* __restrict__ sums1) {
    __shared__ u16 bsm[20480];   // 40 KB, W in fragment order
    __shared__ float bs[256];
    const int tx = threadIdx.x, lane = tx & 63, w = tx >> 6;
    const int mrow = lane & 15, quad = lane >> 4;

    const int r0 = blockIdx.x * 128 + w * 16 + mrow;
    const int s0 = sidx[r0];
    const int n0 = nidx[r0];
    const u16* pa0 = ab + (size_t)s0 * 64 + quad * 8;
    const u16* pb0 = ab + (size_t)n0 * 64 + quad * 8;
    const float* p0 = nbr + (size_t)r0 * 32 + quad * 8;

    // All 5 A-fragments issued up front; latency overlaps W staging below.
    bf16x8 a0 = *(const bf16x8*)(pa0);
    bf16x8 a1 = *(const bf16x8*)(pa0 + 32);
    bf16x8 a2 = *(const bf16x8*)(pb0);
    bf16x8 a3 = *(const bf16x8*)(pb0 + 32);
    bf16x8 a4 = cvt8v(*(const f32x4*)p0, *(const f32x4*)(p0 + 4));
    *(bf16x8*)(nbrb + (size_t)r0 * 32 + quad * 8) = a4;

    if (tx < 256) bs[tx] = 0.0f;
#pragma unroll
    for (int i = 0; i < 5; i++) {
        int idx = (i * 512 + tx) * 8;    // 8 KB per block-wide iteration
        *(bf16x8*)&bsm[idx] = *(const bf16x8*)&wf[idx];
    }
    __syncthreads();

    f32x4 acc[8];
#pragma unroll
    for (int ct = 0; ct < 8; ct++) { f32x4 z = {0.f, 0.f, 0.f, 0.f}; acc[ct] = z; }

#pragma unroll
    for (int kt = 0; kt < 5; kt++) {
        bf16x8 a = (kt == 0) ? a0 : (kt == 1) ? a1 : (kt == 2) ? a2 : (kt == 3) ? a3 : a4;
#pragma unroll
        for (int ct = 0; ct < 8; ct++) {
            bf16x8 b = *(const bf16x8*)&bsm[((kt * 8 + ct) * 64 + lane) * 8];
            acc[ct] = __builtin_amdgcn_mfma_f32_16x16x32_bf16(a, b, acc[ct], 0, 0, 0);
        }
    }

    // Stats: C/D col = ct*16+mrow, row = quad*4+rg; reduce rows via shfl
#pragma unroll
    for (int ct = 0; ct < 8; ct++) {
        float s = 0.f, q = 0.f;
#pragma unroll
        for (int rg = 0; rg < 4; rg++) {
            float v = acc[ct][rg];
            s += v; q += v * v;
        }
        s += __shfl_xor(s, 16, 64); s += __shfl_xor(s, 32, 64);
        q += __shfl_xor(q, 16, 64); q += __shfl_xor(q, 32, 64);
        if (quad == 0) {
            atomicAdd(&bs[ct * 16 + mrow], s);
            atomicAdd(&bs[128 + ct * 16 + mrow], q);
        }
    }
    __syncthreads();
    if (tx < 256) atomicAdd(&sums1[tx], bs[tx]);
}

// ---------------------------------------------------------------------------
// k3: GEMM pass 2 + BN1 + sigmoid*softplus + segment-sum.
// R3: W in LDS; after the GEMM the SAME 40KB buffer is reused as the msgb
// transpose scratch (union; barrier separates last W read from first write).
// LDS = 41KB -> 3 blocks/CU = 24 waves (75%), vs 2 blocks (41%) at 298us.
// ---------------------------------------------------------------------------
__global__ __launch_bounds__(512, 6) void k3_msg(const u16* __restrict__ ab,
                                                 const u16* __restrict__ nbrb,
                                                 const int* __restrict__ sidx,
                                                 const int* __restrict__ nidx,
                                                 const u16* __restrict__ wf,
                                                 const float* __restrict__ sums1,
                                                 const float* __restrict__ g1,
                                                 const float* __restrict__ b1,
                                                 float* __restrict__ ns) {
    __shared__ __align__(16) char smraw[40960];      // union: W then msgb
    u16* bsm = (u16*)smraw;                          // 20480 bf16 (40 KB)
    float (*msgb)[16 * 66] = (float(*)[16 * 66])smraw;  // 8 x 4.2 KB = 33.8 KB
    const int tx = threadIdx.x, lane = tx & 63, w = tx >> 6;
    const int mrow = lane & 15, quad = lane >> 4;

    const int rb = blockIdx.x * 128 + w * 16;
    const int r0 = rb + mrow;
    const int s0 = sidx[r0];
    const int n0 = nidx[r0];
    const u16* pa0 = ab + (size_t)s0 * 64 + quad * 8;
    const u16* pb0 = ab + (size_t)n0 * 64 + quad * 8;

    bf16x8 a0 = *(const bf16x8*)(pa0);
    bf16x8 a1 = *(const bf16x8*)(pa0 + 32);
    bf16x8 a2 = *(const bf16x8*)(pb0);
    bf16x8 a3 = *(const bf16x8*)(pb0 + 32);
    bf16x8 a4 = *(const bf16x8*)(nbrb + (size_t)r0 * 32 + quad * 8);

#pragma unroll
    for (int i = 0; i < 5; i++) {
        int idx = (i * 512 + tx) * 8;
        *(bf16x8*)&bsm[idx] = *(const bf16x8*)&wf[idx];
    }
    __syncthreads();

    f32x4 acc[8];
#pragma unroll
    for (int ct = 0; ct < 8; ct++) { f32x4 z = {0.f, 0.f, 0.f, 0.f}; acc[ct] = z; }

#pragma unroll
    for (int kt = 0; kt < 5; kt++) {
        bf16x8 a = (kt == 0) ? a0 : (kt == 1) ? a1 : (kt == 2) ? a2 : (kt == 3) ? a3 : a4;
#pragma unroll
        for (int ct = 0; ct < 8; ct++) {
            bf16x8 b = *(const bf16x8*)&bsm[((kt * 8 + ct) * 64 + lane) * 8];
            acc[ct] = __builtin_amdgcn_mfma_f32_16x16x32_bf16(a, b, acc[ct], 0, 0, 0);
        }
    }

    // BN1 affine constants (fc bias b cancels exactly under training-mode BN)
    const float invE = 1.0f / (float)E_TOT;
    float af[4], kf[4], ac[4], kc[4];
#pragma unroll
    for (int ct = 0; ct < 4; ct++) {
        int cf = ct * 16 + mrow, cc = cf + 64;
        float mf = sums1[cf] * invE;
        float vf = sums1[128 + cf] * invE - mf * mf;
        af[ct] = g1[cf] * rsqrtf(vf + 1e-5f);
        kf[ct] = b1[cf] - af[ct] * mf;
        float mc = sums1[cc] * invE;
        float vc = sums1[128 + cc] * invE - mc * mc;
        ac[ct] = g1[cc] * rsqrtf(vc + 1e-5f);
        kc[ct] = b1[cc] - ac[ct] * mc;
    }

    __syncthreads();   // all waves done reading W before msgb overwrites it

    float* mw = msgb[w];
#pragma unroll
    for (int ct = 0; ct < 4; ct++) {
#pragma unroll
        for (int rg = 0; rg < 4; rg++) {
            // C/D layout: row = quad*4+rg, col = mrow (+16*ct)
            float xf = af[ct] * acc[ct][rg] + kf[ct];
            float xc = ac[ct] * acc[ct + 4][rg] + kc[ct];
            float sg = 1.0f / (1.0f + __expf(-xf));
            mw[(quad * 4 + rg) * 66 + ct * 16 + mrow] = sg * softplus_f(xc);
        }
    }

    // Segment-sum scan over the wave's 16 rows (LDS transpose read: lane=col)
    float accum = 0.f;
    int cur = sidx[rb];
#pragma unroll
    for (int i = 0; i < 16; i++) {
        int idx = sidx[rb + i];   // wave-uniform -> scalar loads
        if (idx != cur) {
            atomicAdd(&ns[(size_t)cur * 64 + lane], accum);
            accum = 0.f;
            cur = idx;
        }
        accum += mw[i * 66 + lane];
    }
    atomicAdd(&ns[(size_t)cur * 64 + lane], accum);
}

// ---------------------------------------------------------------------------
// k4: BN2 stats over nbr_sumed (N x 64 f32) -> sums2[128]
// ---------------------------------------------------------------------------
__global__ __launch_bounds__(256) void k4_bn2stats(const float* __restrict__ ns,
                                                   float* __restrict__ sums2) {
    const int tx = threadIdx.x;
    const int col = tx & 63, rg = tx >> 6;
    float s = 0.f, q = 0.f;
    for (int r = blockIdx.x * 4 + rg; r < N_AT; r += 256 * 4) {
        float v = ns[r * 64 + col];
        s += v; q += v * v;
    }
    atomicAdd(&sums2[col], s);
    atomicAdd(&sums2[64 + col], q);
}

// ---------------------------------------------------------------------------
// k5: out = softplus(atom + BN2(nbr_sumed))
// ---------------------------------------------------------------------------
__global__ __launch_bounds__(256) void k5_final(const float* __restrict__ atom,
                                                const float* __restrict__ ns,
                                                const float* __restrict__ sums2,
                                                const float* __restrict__ g2,
                                                const float* __restrict__ b2,
                                                float* __restrict__ out) {
    const int i = blockIdx.x * 256 + threadIdx.x;  // grid covers N*64 exactly
    const int col = i & 63;
    const float invN = 1.0f / (float)N_AT;
    float mean = sums2[col] * invN;
    float var = sums2[64 + col] * invN - mean * mean;
    float a2 = g2[col] * rsqrtf(var + 1e-5f);
    float c2 = b2[col] - a2 * mean;
    out[i] = softplus_f(atom[i] + a2 * ns[i] + c2);
}

extern "C" void kernel_launch(void* const* d_in, const int* in_sizes, int n_in,
                              void* d_out, int out_size, void* d_ws, size_t ws_size,
                              hipStream_t stream) {
    const float* atom = (const float*)d_in[0];
    const float* nbr  = (const float*)d_in[1];
    const int* sidx   = (const int*)d_in[2];
    const int* nidx   = (const int*)d_in[3];
    const float* W    = (const float*)d_in[4];
    // d_in[5] = b : cancels exactly under training-mode BN1 -> unused
    const float* g1   = (const float*)d_in[6];
    const float* b1   = (const float*)d_in[7];
    const float* g2   = (const float*)d_in[8];
    const float* b2   = (const float*)d_in[9];
    float* out = (float*)d_out;

    char* ws = (char*)d_ws;
    float* sums1 = (float*)(ws + SUM1_OFF);
    float* sums2 = (float*)(ws + SUM2_OFF);
    u16*   wf    = (u16*)(ws + WF_OFF);
    float* nsum  = (float*)(ws + NS_OFF);
    u16*   ab    = (u16*)(ws + AB_OFF);
    u16*   nbrb  = (u16*)(ws + NBRB_OFF);

    k_setup<<<1024, 256, 0, stream>>>(atom, W, ws);
    k1_stats<<<E_TOT / 128, 512, 0, stream>>>(ab, nbr, nbrb, sidx, nidx, wf, sums1);
    k3_msg<<<E_TOT / 128, 512, 0, stream>>>(ab, nbrb, sidx, nidx, wf, sums1, g1, b1, nsum);
    k4_bn2stats<<<256, 256, 0, stream>>>(nsum, sums2);
    k5_final<<<(N_AT * 64) / 256, 256, 0, stream>>>(atom, nsum, sums2, g2, b2, out);
}

// Round 5
// 709.193 us; speedup vs baseline: 3.0332x; 1.1738x over previous
//
#include <hip/hip_runtime.h>

#define E_TOT 1600000
#define N_AT  50000
#define NB1   (E_TOT / 128)   // k1/k3 grid = 12500 blocks

typedef unsigned short u16;
typedef __attribute__((ext_vector_type(8))) __bf16 bf16x8;
typedef __attribute__((ext_vector_type(4))) __bf16 bf16x4;
typedef __attribute__((ext_vector_type(4))) float f32x4;

// Workspace layout (byte offsets), all 16B-aligned:
//   [0,       1024)   sums1 (256 f32)  -- zeroed by k_setup
//   [1024,    1536)   sums2 (128 f32)  -- zeroed by k_setup
//   [2048,   43008)   wf    (20480 bf16, B-fragment order) -- written by k_setup
//   [43008, +12.8M)   ns    (N*64 f32) -- zeroed by k_setup
//   [+,      +6.4M)   ab    (N*64 bf16) -- written by k_setup
//   [+,    +102.4M)   nbrb  (E*32 bf16) -- written by k1
//   [+,     +12.8M)   part  (NB1*256 f32) -- written by k1, reduced by k2
#define SUM1_OFF 0
#define SUM2_OFF 1024
#define WF_OFF   2048
#define NS_OFF   43008
#define AB_OFF   12843008
#define NBRB_OFF 19243008
#define PART_OFF 121643008

__device__ __forceinline__ u16 f2bf(float f) {
    unsigned int u = __float_as_uint(f);
    return (u16)((u + 0x7FFFu + ((u >> 16) & 1u)) >> 16);
}
__device__ __forceinline__ float softplus_f(float x) {
    return fmaxf(x, 0.0f) + __logf(1.0f + __expf(-fabsf(x)));
}
__device__ __forceinline__ bf16x8 cvt8v(f32x4 a, f32x4 b) {
    bf16x8 r;
    r[0] = (__bf16)a[0]; r[1] = (__bf16)a[1]; r[2] = (__bf16)a[2]; r[3] = (__bf16)a[3];
    r[4] = (__bf16)b[0]; r[5] = (__bf16)b[1]; r[6] = (__bf16)b[2]; r[7] = (__bf16)b[3];
    return r;
}
// Async global->LDS DMA, 16B per lane (wave-uniform LDS base + lane*16 layout).
__device__ __forceinline__ void ldsdma16(void* lds, const void* g) {
    __builtin_amdgcn_global_load_lds(
        (const __attribute__((address_space(1))) unsigned int*)g,
        (__attribute__((address_space(3))) unsigned int*)lds, 16, 0, 0);
}

// ---------------------------------------------------------------------------
// k_setup: zero sums1/sums2/ns + cvt atom->ab + swizzle W->wf
// ---------------------------------------------------------------------------
__global__ __launch_bounds__(256) void k_setup(const float* __restrict__ atom,
                                               const float* __restrict__ W,
                                               char* __restrict__ ws) {
    u16* wf   = (u16*)(ws + WF_OFF);
    float* ns = (float*)(ws + NS_OFF);
    u16* ab   = (u16*)(ws + AB_OFF);
    const int tid = blockIdx.x * 256 + threadIdx.x;
    const int gsz = gridDim.x * 256;

    for (int i = tid; i < 512; i += gsz) ((float*)ws)[i] = 0.0f;  // sums1+sums2

    f32x4 z = {0.f, 0.f, 0.f, 0.f};
    for (int i = tid; i < N_AT * 64 / 4; i += gsz) ((f32x4*)ns)[i] = z;

    for (int i = tid; i < N_AT * 64 / 4; i += gsz) {
        f32x4 v = ((const f32x4*)atom)[i];
        bf16x4 h;
        h[0] = (__bf16)v[0]; h[1] = (__bf16)v[1];
        h[2] = (__bf16)v[2]; h[3] = (__bf16)v[3];
        *(bf16x4*)(ab + i * 4) = h;
    }

    for (int t = tid; t < 20480; t += gsz) {
        int j = t & 7, l2 = (t >> 3) & 63, ct = (t >> 9) & 7, kt = t >> 12;
        int k = kt * 32 + (l2 >> 4) * 8 + j;
        int c = ct * 16 + (l2 & 15);
        wf[t] = f2bf(W[k * 128 + c]);
    }
}

// ---------------------------------------------------------------------------
// k1: GEMM pass 1 (stats) + nbr->bf16 cvt.
// R4: (a) W staged via global_load_lds (no VGPR round-trip -> no spill; R3's
// register staging spilled ~8 f32/thread = 205MB of scratch writes);
// (b) sums1 global atomics (3.2M RMW onto 16 cachelines) replaced by plain
// per-block partial store + k2_red reduction. Zero global atomics here.
// LDS = 40KB W + 1KB bs -> 3 blocks/CU = 24 waves.
// ---------------------------------------------------------------------------
__global__ __launch_bounds__(512, 6) void k1_stats(const u16* __restrict__ ab,
                                                   const float* __restrict__ nbr,
                                                   u16* __restrict__ nbrb,
                                                   const int* __restrict__ sidx,
                                                   const int* __restrict__ nidx,
                                                   const u16* __restrict__ wf,
                                                   float* __restrict__ part) {
    __shared__ __align__(16) u16 bsm[20480];   // 40 KB, W in fragment order
    __shared__ float bs[256];
    const int tx = threadIdx.x, lane = tx & 63, w = tx >> 6;
    const int mrow = lane & 15, quad = lane >> 4;

    // Async W stage: issues immediately, no registers consumed.
#pragma unroll
    for (int i = 0; i < 5; i++) {
        int off = (i * 512 + tx) * 16;   // byte offset, linear in lane
        ldsdma16((char*)bsm + off, (const char*)wf + off);
    }

    const int r0 = blockIdx.x * 128 + w * 16 + mrow;
    const int s0 = sidx[r0];
    const int n0 = nidx[r0];
    const u16* pa0 = ab + (size_t)s0 * 64 + quad * 8;
    const u16* pb0 = ab + (size_t)n0 * 64 + quad * 8;
    const float* p0 = nbr + (size_t)r0 * 32 + quad * 8;

    // All 5 A-fragments issued up front; latency overlaps W staging.
    bf16x8 a0 = *(const bf16x8*)(pa0);
    bf16x8 a1 = *(const bf16x8*)(pa0 + 32);
    bf16x8 a2 = *(const bf16x8*)(pb0);
    bf16x8 a3 = *(const bf16x8*)(pb0 + 32);
    bf16x8 a4 = cvt8v(*(const f32x4*)p0, *(const f32x4*)(p0 + 4));
    *(bf16x8*)(nbrb + (size_t)r0 * 32 + quad * 8) = a4;

    if (tx < 256) bs[tx] = 0.0f;
    __syncthreads();   // drains vmcnt -> W staging complete

    f32x4 acc[8];
#pragma unroll
    for (int ct = 0; ct < 8; ct++) { f32x4 z = {0.f, 0.f, 0.f, 0.f}; acc[ct] = z; }

#pragma unroll
    for (int kt = 0; kt < 5; kt++) {
        bf16x8 a = (kt == 0) ? a0 : (kt == 1) ? a1 : (kt == 2) ? a2 : (kt == 3) ? a3 : a4;
#pragma unroll
        for (int ct = 0; ct < 8; ct++) {
            bf16x8 b = *(const bf16x8*)&bsm[((kt * 8 + ct) * 64 + lane) * 8];
            acc[ct] = __builtin_amdgcn_mfma_f32_16x16x32_bf16(a, b, acc[ct], 0, 0, 0);
        }
    }

    // Stats: C/D col = ct*16+mrow, row = quad*4+rg; reduce rows via shfl
#pragma unroll
    for (int ct = 0; ct < 8; ct++) {
        float s = 0.f, q = 0.f;
#pragma unroll
        for (int rg = 0; rg < 4; rg++) {
            float v = acc[ct][rg];
            s += v; q += v * v;
        }
        s += __shfl_xor(s, 16, 64); s += __shfl_xor(s, 32, 64);
        q += __shfl_xor(q, 16, 64); q += __shfl_xor(q, 32, 64);
        if (quad == 0) {
            atomicAdd(&bs[ct * 16 + mrow], s);
            atomicAdd(&bs[128 + ct * 16 + mrow], q);
        }
    }
    __syncthreads();
    if (tx < 256) part[(size_t)blockIdx.x * 256 + tx] = bs[tx];  // plain store
}

// ---------------------------------------------------------------------------
// k2_red: part[NB1][256] -> sums1[256]. 256 blocks, coalesced column reduce.
// 65k low-contention atomics total (50x fewer than before, spread over time).
// ---------------------------------------------------------------------------
__global__ __launch_bounds__(256) void k2_red(const float* __restrict__ part,
                                              float* __restrict__ sums1) {
    const int tx = threadIdx.x;
    float s = 0.f;
    for (int r = blockIdx.x; r < NB1; r += 256) s += part[(size_t)r * 256 + tx];
    atomicAdd(&sums1[tx], s);
}

// ---------------------------------------------------------------------------
// k3: GEMM pass 2 + BN1 + sigmoid*softplus + segment-sum.
// R4: W staged via global_load_lds; same 40KB buffer reused as msgb transpose
// scratch after the GEMM (union, barrier-separated). 3 blocks/CU.
// ---------------------------------------------------------------------------
__global__ __launch_bounds__(512, 6) void k3_msg(const u16* __restrict__ ab,
                                                 const u16* __restrict__ nbrb,
                                                 const int* __restrict__ sidx,
                                                 const int* __restrict__ nidx,
                                                 const u16* __restrict__ wf,
                                                 const float* __restrict__ sums1,
                                                 const float* __restrict__ g1,
                                                 const float* __restrict__ b1,
                                                 float* __restrict__ ns) {
    __shared__ __align__(16) char smraw[40960];      // union: W then msgb
    u16* bsm = (u16*)smraw;                          // 20480 bf16 (40 KB)
    float (*msgb)[16 * 66] = (float(*)[16 * 66])smraw;  // 8 x 4.2 KB = 33.8 KB
    const int tx = threadIdx.x, lane = tx & 63, w = tx >> 6;
    const int mrow = lane & 15, quad = lane >> 4;

#pragma unroll
    for (int i = 0; i < 5; i++) {
        int off = (i * 512 + tx) * 16;
        ldsdma16(smraw + off, (const char*)wf + off);
    }

    const int rb = blockIdx.x * 128 + w * 16;
    const int r0 = rb + mrow;
    const int s0 = sidx[r0];
    const int n0 = nidx[r0];
    const u16* pa0 = ab + (size_t)s0 * 64 + quad * 8;
    const u16* pb0 = ab + (size_t)n0 * 64 + quad * 8;

    bf16x8 a0 = *(const bf16x8*)(pa0);
    bf16x8 a1 = *(const bf16x8*)(pa0 + 32);
    bf16x8 a2 = *(const bf16x8*)(pb0);
    bf16x8 a3 = *(const bf16x8*)(pb0 + 32);
    bf16x8 a4 = *(const bf16x8*)(nbrb + (size_t)r0 * 32 + quad * 8);

    __syncthreads();   // drains vmcnt -> W staging complete

    f32x4 acc[8];
#pragma unroll
    for (int ct = 0; ct < 8; ct++) { f32x4 z = {0.f, 0.f, 0.f, 0.f}; acc[ct] = z; }

#pragma unroll
    for (int kt = 0; kt < 5; kt++) {
        bf16x8 a = (kt == 0) ? a0 : (kt == 1) ? a1 : (kt == 2) ? a2 : (kt == 3) ? a3 : a4;
#pragma unroll
        for (int ct = 0; ct < 8; ct++) {
            bf16x8 b = *(const bf16x8*)&bsm[((kt * 8 + ct) * 64 + lane) * 8];
            acc[ct] = __builtin_amdgcn_mfma_f32_16x16x32_bf16(a, b, acc[ct], 0, 0, 0);
        }
    }

    // BN1 affine constants (fc bias b cancels exactly under training-mode BN)
    const float invE = 1.0f / (float)E_TOT;
    float af[4], kf[4], ac[4], kc[4];
#pragma unroll
    for (int ct = 0; ct < 4; ct++) {
        int cf = ct * 16 + mrow, cc = cf + 64;
        float mf = sums1[cf] * invE;
        float vf = sums1[128 + cf] * invE - mf * mf;
        af[ct] = g1[cf] * rsqrtf(vf + 1e-5f);
        kf[ct] = b1[cf] - af[ct] * mf;
        float mc = sums1[cc] * invE;
        float vc = sums1[128 + cc] * invE - mc * mc;
        ac[ct] = g1[cc] * rsqrtf(vc + 1e-5f);
        kc[ct] = b1[cc] - ac[ct] * mc;
    }

    __syncthreads();   // all waves done reading W before msgb overwrites it

    float* mw = msgb[w];
#pragma unroll
    for (int ct = 0; ct < 4; ct++) {
#pragma unroll
        for (int rg = 0; rg < 4; rg++) {
            // C/D layout: row = quad*4+rg, col = mrow (+16*ct)
            float xf = af[ct] * acc[ct][rg] + kf[ct];
            float xc = ac[ct] * acc[ct + 4][rg] + kc[ct];
            float sg = 1.0f / (1.0f + __expf(-xf));
            mw[(quad * 4 + rg) * 66 + ct * 16 + mrow] = sg * softplus_f(xc);
        }
    }

    // Segment-sum scan over the wave's 16 rows (LDS transpose read: lane=col)
    float accum = 0.f;
    int cur = sidx[rb];
#pragma unroll
    for (int i = 0; i < 16; i++) {
        int idx = sidx[rb + i];   // wave-uniform -> scalar loads
        if (idx != cur) {
            atomicAdd(&ns[(size_t)cur * 64 + lane], accum);
            accum = 0.f;
            cur = idx;
        }
        accum += mw[i * 66 + lane];
    }
    atomicAdd(&ns[(size_t)cur * 64 + lane], accum);
}

// ---------------------------------------------------------------------------
// k4: BN2 stats over nbr_sumed (N x 64 f32) -> sums2[128]
// ---------------------------------------------------------------------------
__global__ __launch_bounds__(256) void k4_bn2stats(const float* __restrict__ ns,
                                                   float* __restrict__ sums2) {
    const int tx = threadIdx.x;
    const int col = tx & 63, rg = tx >> 6;
    float s = 0.f, q = 0.f;
    for (int r = blockIdx.x * 4 + rg; r < N_AT; r += 256 * 4) {
        float v = ns[r * 64 + col];
        s += v; q += v * v;
    }
    atomicAdd(&sums2[col], s);
    atomicAdd(&sums2[64 + col], q);
}

// ---------------------------------------------------------------------------
// k5: out = softplus(atom + BN2(nbr_sumed))
// ---------------------------------------------------------------------------
__global__ __launch_bounds__(256) void k5_final(const float* __restrict__ atom,
                                                const float* __restrict__ ns,
                                                const float* __restrict__ sums2,
                                                const float* __restrict__ g2,
                                                const float* __restrict__ b2,
                                                float* __restrict__ out) {
    const int i = blockIdx.x * 256 + threadIdx.x;  // grid covers N*64 exactly
    const int col = i & 63;
    const float invN = 1.0f / (float)N_AT;
    float mean = sums2[col] * invN;
    float var = sums2[64 + col] * invN - mean * mean;
    float a2 = g2[col] * rsqrtf(var + 1e-5f);
    float c2 = b2[col] - a2 * mean;
    out[i] = softplus_f(atom[i] + a2 * ns[i] + c2);
}

extern "C" void kernel_launch(void* const* d_in, const int* in_sizes, int n_in,
                              void* d_out, int out_size, void* d_ws, size_t ws_size,
                              hipStream_t stream) {
    const float* atom = (const float*)d_in[0];
    const float* nbr  = (const float*)d_in[1];
    const int* sidx   = (const int*)d_in[2];
    const int* nidx   = (const int*)d_in[3];
    const float* W    = (const float*)d_in[4];
    // d_in[5] = b : cancels exactly under training-mode BN1 -> unused
    const float* g1   = (const float*)d_in[6];
    const float* b1   = (const float*)d_in[7];
    const float* g2   = (const float*)d_in[8];
    const float* b2   = (const float*)d_in[9];
    float* out = (float*)d_out;

    char* ws = (char*)d_ws;
    float* sums1 = (float*)(ws + SUM1_OFF);
    float* sums2 = (float*)(ws + SUM2_OFF);
    u16*   wf    = (u16*)(ws + WF_OFF);
    float* nsum  = (float*)(ws + NS_OFF);
    u16*   ab    = (u16*)(ws + AB_OFF);
    u16*   nbrb  = (u16*)(ws + NBRB_OFF);
    float* part  = (float*)(ws + PART_OFF);

    k_setup<<<1024, 256, 0, stream>>>(atom, W, ws);
    k1_stats<<<NB1, 512, 0, stream>>>(ab, nbr, nbrb, sidx, nidx, wf, part);
    k2_red<<<256, 256, 0, stream>>>(part, sums1);
    k3_msg<<<NB1, 512, 0, stream>>>(ab, nbrb, sidx, nidx, wf, sums1, g1, b1, nsum);
    k4_bn2stats<<<256, 256, 0, stream>>>(nsum, sums2);
    k5_final<<<(N_AT * 64) / 256, 256, 0, stream>>>(atom, nsum, sums2, g2, b2, out);
}